// Round 1
// baseline (627.653 us; speedup 1.0000x reference)
//
#include <hip/hip_runtime.h>
#include <hip/hip_bf16.h>
#include <cstdint>

// Problem: B=256, H=128, N=1000.
// logits[b,n] = sum_h v[h] * tanh( sum_{k<384} W[h,k]*X[b,k,n] + cterm[b,h] )
// out[b,n]    = softmax_n(logits[b,:])
// X = concat(adj, static, dyn) along k; cterm = W[:,384:512] @ dec[b].
// Strategy: bf16 MFMA 16x16x32 with Markidis hi/lo split (fp32-equivalent accuracy),
// memory-bound at ~393 MB of X reads.

#define BB 256
#define HH 128
#define NN 1000
#define K3 384

typedef __attribute__((ext_vector_type(8))) short short8;
typedef __attribute__((ext_vector_type(4))) float f32x4;

__device__ __forceinline__ uint16_t bf16_rne(float f) {
    uint32_t u = __float_as_uint(f);
    u += 0x7FFFu + ((u >> 16) & 1u);
    return (uint16_t)(u >> 16);
}
__device__ __forceinline__ float bf16_as_f32(uint16_t h) {
    return __uint_as_float(((uint32_t)h) << 16);
}
__device__ __forceinline__ float fast_tanh(float x) {
    // tanh(x) = 1 - 2/(exp(2x)+1); exact at +-inf saturation, ~1e-6 rel err.
    float e = __expf(2.0f * x);
    return 1.0f - 2.0f * __builtin_amdgcn_rcpf(e + 1.0f);
}

// ---------------- prep: W split + cterm ----------------
__global__ void prep_kernel(const float* __restrict__ W, const float* __restrict__ dec,
                            uint16_t* __restrict__ Whi, uint16_t* __restrict__ Wlo,
                            float* __restrict__ cterm) {
    int idx = blockIdx.x * 256 + threadIdx.x;
    if (blockIdx.x < 192) {
        // split W[:, :384] into hi/lo bf16 ; 128*384 = 49152 elements
        if (idx < HH * K3) {
            int h = idx / K3, k = idx - h * K3;
            float w = W[h * 512 + k];
            uint16_t hi = bf16_rne(w);
            float wl = w - bf16_as_f32(hi);
            Whi[idx] = hi;
            Wlo[idx] = bf16_rne(wl);
        }
    } else {
        // cterm[b,h] = sum_k W[h, 384+k] * dec[b,k]   (fp32)
        int j = idx - 192 * 256;
        if (j < BB * HH) {
            int b = j >> 7, h = j & 127;
            const float* wrow = W + h * 512 + 384;
            const float* d = dec + b * HH;
            float s = 0.0f;
#pragma unroll 8
            for (int k = 0; k < HH; ++k) s += wrow[k] * d[k];
            cterm[j] = s;
        }
    }
}

// ---------------- main: GEMM + tanh + v-dot -> logits ----------------
__launch_bounds__(256, 4)
__global__ void attn_main(const float* __restrict__ adj, const float* __restrict__ sta,
                          const float* __restrict__ dyn,
                          const uint16_t* __restrict__ Whi, const uint16_t* __restrict__ Wlo,
                          const float* __restrict__ cterm, const float* __restrict__ vvec,
                          float* __restrict__ logits) {
    const int tid = threadIdx.x;
    const int wave = tid >> 6;
    const int lane = tid & 63;
    const int c = lane & 15;   // MFMA "outer" lane index: A row sel / B col sel / C col sel
    const int q = lane >> 4;   // k-group (inputs) / row-quad (output)

    const int b = blockIdx.x >> 4;        // batch
    const int tile = blockIdx.x & 15;     // 64-wide n tile
    const int n = tile * 64 + wave * 16 + c;
    const int ncl = (n < NN) ? n : (NN - 1);  // clamp loads in tail tile

    f32x4 acc[8];
#pragma unroll
    for (int m = 0; m < 8; ++m) acc[m] = (f32x4){0.f, 0.f, 0.f, 0.f};

    union frag_u { uint32_t u[4]; short8 s; };

    const long bbase = (long)b * HH * NN;

#pragma unroll
    for (int t = 0; t < 3; ++t) {
        const float* base = (t == 0 ? adj : (t == 1 ? sta : dyn)) + bbase;
#pragma unroll
        for (int cc = 0; cc < 4; ++cc) {
            const int k0 = t * 128 + cc * 32;           // global k of this 32-chunk
            const float* p = base + (cc * 32 + 8 * q) * NN + ncl;
            float x[8];
#pragma unroll
            for (int j = 0; j < 8; ++j) x[j] = p[j * NN];

            // hi/lo split, packed into MFMA B-fragments (element j = k-offset 8q+j)
            frag_u bh, bl;
#pragma unroll
            for (int j = 0; j < 4; ++j) {
                uint16_t h0 = bf16_rne(x[2 * j]);
                uint16_t h1 = bf16_rne(x[2 * j + 1]);
                float l0 = x[2 * j]     - bf16_as_f32(h0);
                float l1 = x[2 * j + 1] - bf16_as_f32(h1);
                bh.u[j] = (uint32_t)h0 | ((uint32_t)h1 << 16);
                bl.u[j] = (uint32_t)bf16_rne(l0) | ((uint32_t)bf16_rne(l1) << 16);
            }

#pragma unroll
            for (int m = 0; m < 8; ++m) {
                const int woff = (m * 16 + c) * K3 + k0 + 8 * q;
                short8 ahi = *(const short8*)(Whi + woff);
                short8 alo = *(const short8*)(Wlo + woff);
                acc[m] = __builtin_amdgcn_mfma_f32_16x16x32_bf16(ahi, bh.s, acc[m], 0, 0, 0);
                acc[m] = __builtin_amdgcn_mfma_f32_16x16x32_bf16(ahi, bl.s, acc[m], 0, 0, 0);
                acc[m] = __builtin_amdgcn_mfma_f32_16x16x32_bf16(alo, bh.s, acc[m], 0, 0, 0);
            }
        }
    }

    // Epilogue: C layout col=lane&15, row=(lane>>4)*4+r ; h = m*16 + q*4 + r
    const float* ct = cterm + b * HH;
    float s = 0.0f;
#pragma unroll
    for (int m = 0; m < 8; ++m) {
#pragma unroll
        for (int r = 0; r < 4; ++r) {
            const int h = m * 16 + q * 4 + r;
            float y = acc[m][r] + ct[h];
            s += vvec[h] * fast_tanh(y);
        }
    }
    // reduce over the 4 row-quads (same column c)
    s += __shfl_xor(s, 16, 64);
    s += __shfl_xor(s, 32, 64);
    if (lane < 16 && n < NN) logits[b * NN + n] = s;
}

// ---------------- softmax over n, in place on d_out ----------------
__global__ void softmax_kernel(float* __restrict__ out) {
    const int b = blockIdx.x;
    const int tid = threadIdx.x;
    float* row = out + b * NN;

    float vals[4];
#pragma unroll
    for (int i = 0; i < 4; ++i) {
        int j = tid + i * 256;
        vals[i] = (j < NN) ? row[j] : -1e30f;
    }
    float mx = fmaxf(fmaxf(vals[0], vals[1]), fmaxf(vals[2], vals[3]));
#pragma unroll
    for (int off = 1; off < 64; off <<= 1) mx = fmaxf(mx, __shfl_xor(mx, off, 64));
    __shared__ float smax[4];
    if ((tid & 63) == 0) smax[tid >> 6] = mx;
    __syncthreads();
    mx = fmaxf(fmaxf(smax[0], smax[1]), fmaxf(smax[2], smax[3]));

    float e[4];
    float s = 0.0f;
#pragma unroll
    for (int i = 0; i < 4; ++i) {
        int j = tid + i * 256;
        e[i] = (j < NN) ? __expf(vals[i] - mx) : 0.0f;
        s += e[i];
    }
#pragma unroll
    for (int off = 1; off < 64; off <<= 1) s += __shfl_xor(s, off, 64);
    __shared__ float ssum[4];
    if ((tid & 63) == 0) ssum[tid >> 6] = s;
    __syncthreads();
    s = ssum[0] + ssum[1] + ssum[2] + ssum[3];
    float inv = 1.0f / s;
#pragma unroll
    for (int i = 0; i < 4; ++i) {
        int j = tid + i * 256;
        if (j < NN) row[j] = e[i] * inv;
    }
}

extern "C" void kernel_launch(void* const* d_in, const int* in_sizes, int n_in,
                              void* d_out, int out_size, void* d_ws, size_t ws_size,
                              hipStream_t stream) {
    const float* adj = (const float*)d_in[0];
    const float* sta = (const float*)d_in[1];
    const float* dyn = (const float*)d_in[2];
    const float* dec = (const float*)d_in[3];
    const float* v   = (const float*)d_in[4];
    const float* W   = (const float*)d_in[5];

    uint16_t* Whi = (uint16_t*)d_ws;                    // 128*384*2 = 98304 B
    uint16_t* Wlo = Whi + HH * K3;                      // 98304 B
    float* cterm  = (float*)(Wlo + HH * K3);            // 256*128*4 = 131072 B
    float* logits = (float*)d_out;                      // reuse output buffer for logits

    prep_kernel<<<320, 256, 0, stream>>>(W, dec, Whi, Wlo, cterm);
    attn_main<<<BB * 16, 256, 0, stream>>>(adj, sta, dyn, Whi, Wlo, cterm, v, logits);
    softmax_kernel<<<BB, 256, 0, stream>>>(logits);
}

// Round 3
// 368.884 us; speedup vs baseline: 1.7015x; 1.7015x over previous
//
#include <hip/hip_runtime.h>
#include <hip/hip_bf16.h>
#include <cstdint>

// B=256, H=128, N=1000.
// logits[b,n] = sum_h v[h] * tanh( sum_{k<384} W[h,k]*X[b,k,n] + cterm[b,h] )
// out[b,n]    = softmax_n(logits[b,:])
// X = concat(adj, static, dyn); cterm = W[:,384:512] @ dec[b].
// Round 3: fix R2's W-staging bug (48 x 16B chunks per 768B row, not 24).
// Wh(bf16) in LDS once per block; K-loop vmem = X stream only, 1-iter prefetch.

#define BB 256
#define HH 128
#define NN 1000
#define K3 384
#define WROW 784                 // LDS bytes per Wh row: 384*2 + 16 pad (16B-aligned)
#define WLDS (HH * WROW)         // 100352
#define CT_OFF WLDS              // cterm row (128 f32)
#define VV_OFF (WLDS + 512)      // v vector (128 f32)
#define SMEM_ATTN (WLDS + 1024)  // 101376 B

typedef __attribute__((ext_vector_type(8))) short short8;
typedef __attribute__((ext_vector_type(4))) float f32x4;

__device__ __forceinline__ uint32_t pk_bf16_rn(float a, float b) {
    union { __hip_bfloat162 h2; uint32_t u; } cv;
    cv.h2 = __float22bfloat162_rn(make_float2(a, b));
    return cv.u;
}
__device__ __forceinline__ float fast_tanh(float x) {
    float e = __expf(2.0f * x);
    return 1.0f - 2.0f * __builtin_amdgcn_rcpf(e + 1.0f);
}

// ---------------- prep: W split (bf16 hi only) + cterm mini-GEMM ----------------
__global__ void prep_kernel(const float* __restrict__ W, const float* __restrict__ dec,
                            uint16_t* __restrict__ Whi, float* __restrict__ cterm) {
    extern __shared__ float ls[];
    const int tid = threadIdx.x;
    if (blockIdx.x < 48) {
        // W[:, :384] -> bf16 ; 12288 float4 chunks, coalesced
        int idx4 = blockIdx.x * 256 + tid;
        int h = idx4 / 96, k4 = idx4 - h * 96;
        float4 w = *(const float4*)(W + h * 512 + k4 * 4);
        uint2 o;
        o.x = pk_bf16_rn(w.x, w.y);
        o.y = pk_bf16_rn(w.z, w.w);
        *(uint2*)(Whi + h * K3 + k4 * 4) = o;
    } else {
        // cterm[b,h] = sum_k W[h,384+k]*dec[b,k]; 8 b per block, W4+dec in LDS
        float* w4 = ls;              // 128 x 129 (padded, conflict-free)
        float* dl = ls + 128 * 129;  // 8 x 128
        const int bb = (blockIdx.x - 48) * 8;
#pragma unroll
        for (int i = 0; i < 16; ++i) {
            int chunk = tid + i * 256;
            int h = chunk >> 5, kq = chunk & 31;
            float4 v = *(const float4*)(W + h * 512 + 384 + kq * 4);
            float* d = w4 + h * 129 + kq * 4;
            d[0] = v.x; d[1] = v.y; d[2] = v.z; d[3] = v.w;
        }
        {
            float4 dv = *(const float4*)(dec + bb * HH + tid * 4);
            float* d = dl + tid * 4;
            d[0] = dv.x; d[1] = dv.y; d[2] = dv.z; d[3] = dv.w;
        }
        __syncthreads();
#pragma unroll
        for (int r = 0; r < 4; ++r) {
            int o = tid + r * 256;
            int h = o & 127, bl_ = o >> 7;
            const float* wr = w4 + h * 129;
            const float* dr = dl + bl_ * 128;
            float s = 0.f;
#pragma unroll 8
            for (int k = 0; k < 128; ++k) s += wr[k] * dr[k];
            cterm[(bb + bl_) * HH + h] = s;
        }
    }
}

// ---------------- main: GEMM + tanh + v-dot -> logits ----------------
__launch_bounds__(1024, 4)
__global__ void attn_main(const float* __restrict__ adj, const float* __restrict__ sta,
                          const float* __restrict__ dyn,
                          const uint16_t* __restrict__ Whi,
                          const float* __restrict__ cterm, const float* __restrict__ vvec,
                          float* __restrict__ logits) {
    extern __shared__ char smem[];
    const int tid = threadIdx.x;
    const int b = blockIdx.x >> 2;
    const int tile = blockIdx.x & 3;

    // ---- stage Wh into LDS (padded rows): 128 rows x 768 B = 48 x 16B chunks/row ----
#pragma unroll
    for (int i = 0; i < 6; ++i) {
        int ch = tid + i * 1024;            // 6144 chunks of 16 B
        int h = ch / 48, j = ch - h * 48;
        *(uint4*)(smem + h * WROW + j * 16) = *(const uint4*)(Whi + h * K3 + j * 8);
    }
    if (tid < 32) {
        ((float4*)(smem + CT_OFF))[tid] = ((const float4*)(cterm + b * HH))[tid];
    } else if (tid < 64) {
        ((float4*)(smem + VV_OFF))[tid - 32] = ((const float4*)vvec)[tid - 32];
    }
    __syncthreads();

    const int wave = tid >> 6, lane = tid & 63;
    const int c = lane & 15, q = lane >> 4;
    const int n = tile * 256 + wave * 16 + c;
    const int ncl = (n < NN) ? n : NN - 1;
    const long bbase = (long)b * HH * NN;
    const float* A0 = adj + bbase;
    const float* A1 = sta + bbase;
    const float* A2 = dyn + bbase;

    f32x4 acc[8];
#pragma unroll
    for (int m = 0; m < 8; ++m) acc[m] = (f32x4){0.f, 0.f, 0.f, 0.f};

    union fu { uint32_t u[4]; short8 s; };

    float x[8], xn[8];
    {
        const float* p = A0 + (8 * q) * NN + ncl;
#pragma unroll
        for (int j = 0; j < 8; ++j) x[j] = p[j * NN];
    }

#pragma unroll
    for (int it = 0; it < 12; ++it) {
        // prefetch next iteration's X (HBM) before touching this one
        if (it + 1 < 12) {
            const int t2 = (it + 1) >> 2, cc2 = (it + 1) & 3;
            const float* base2 = (t2 == 0) ? A0 : ((t2 == 1) ? A1 : A2);
            const float* p = base2 + (cc2 * 32 + 8 * q) * NN + ncl;
#pragma unroll
            for (int j = 0; j < 8; ++j) xn[j] = p[j * NN];
        }
        // hi/lo split into B-fragments
        fu bh, bl;
#pragma unroll
        for (int j = 0; j < 4; ++j) {
            float a = x[2 * j], d = x[2 * j + 1];
            uint32_t u = pk_bf16_rn(a, d);
            bh.u[j] = u;
            float la = a - __uint_as_float(u << 16);
            float lb = d - __uint_as_float(u & 0xFFFF0000u);
            bl.u[j] = pk_bf16_rn(la, lb);
        }
        // byte offset of this 32-k chunk inside a Wh LDS row
        const int rowoff = (it >> 2) * 256 + (it & 3) * 64 + q * 16;
#pragma unroll
        for (int m = 0; m < 8; ++m) {
            const short8 av = *(const short8*)(smem + (m * 16 + c) * WROW + rowoff);
            acc[m] = __builtin_amdgcn_mfma_f32_16x16x32_bf16(av, bh.s, acc[m], 0, 0, 0);
            acc[m] = __builtin_amdgcn_mfma_f32_16x16x32_bf16(av, bl.s, acc[m], 0, 0, 0);
        }
        if (it + 1 < 12) {
#pragma unroll
            for (int j = 0; j < 8; ++j) x[j] = xn[j];
        }
    }

    // epilogue: C layout col=lane&15, row=q*4+r ; h = m*16 + q*4 + r
    const float* ct = (const float*)(smem + CT_OFF);
    const float* vv = (const float*)(smem + VV_OFF);
    float s = 0.0f;
#pragma unroll
    for (int m = 0; m < 8; ++m) {
#pragma unroll
        for (int r = 0; r < 4; ++r) {
            const int h = m * 16 + q * 4 + r;
            s += vv[h] * fast_tanh(acc[m][r] + ct[h]);
        }
    }
    s += __shfl_xor(s, 16, 64);
    s += __shfl_xor(s, 32, 64);
    if (lane < 16 && n < NN) logits[b * NN + n] = s;
}

// ---------------- softmax over n, in place on d_out ----------------
__global__ void softmax_kernel(float* __restrict__ out) {
    const int b = blockIdx.x;
    const int tid = threadIdx.x;
    float* row = out + b * NN;

    float vals[4];
#pragma unroll
    for (int i = 0; i < 4; ++i) {
        int j = tid + i * 256;
        vals[i] = (j < NN) ? row[j] : -1e30f;
    }
    float mx = fmaxf(fmaxf(vals[0], vals[1]), fmaxf(vals[2], vals[3]));
#pragma unroll
    for (int off = 1; off < 64; off <<= 1) mx = fmaxf(mx, __shfl_xor(mx, off, 64));
    __shared__ float smax[4];
    if ((tid & 63) == 0) smax[tid >> 6] = mx;
    __syncthreads();
    mx = fmaxf(fmaxf(smax[0], smax[1]), fmaxf(smax[2], smax[3]));

    float e[4];
    float s = 0.0f;
#pragma unroll
    for (int i = 0; i < 4; ++i) {
        int j = tid + i * 256;
        e[i] = (j < NN) ? __expf(vals[i] - mx) : 0.0f;
        s += e[i];
    }
#pragma unroll
    for (int off = 1; off < 64; off <<= 1) s += __shfl_xor(s, off, 64);
    __shared__ float ssum[4];
    if ((tid & 63) == 0) ssum[tid >> 6] = s;
    __syncthreads();
    s = ssum[0] + ssum[1] + ssum[2] + ssum[3];
    float inv = 1.0f / s;
#pragma unroll
    for (int i = 0; i < 4; ++i) {
        int j = tid + i * 256;
        if (j < NN) row[j] = e[i] * inv;
    }
}

extern "C" void kernel_launch(void* const* d_in, const int* in_sizes, int n_in,
                              void* d_out, int out_size, void* d_ws, size_t ws_size,
                              hipStream_t stream) {
    const float* adj = (const float*)d_in[0];
    const float* sta = (const float*)d_in[1];
    const float* dyn = (const float*)d_in[2];
    const float* dec = (const float*)d_in[3];
    const float* v   = (const float*)d_in[4];
    const float* W   = (const float*)d_in[5];

    uint16_t* Whi = (uint16_t*)d_ws;                 // 128*384*2 = 98304 B
    float* cterm  = (float*)(Whi + HH * K3);         // 256*128*4 = 131072 B
    float* logits = (float*)d_out;

    prep_kernel<<<80, 256, (128 * 129 + 1024) * 4, stream>>>(W, dec, Whi, cterm);
    attn_main<<<BB * 4, 1024, SMEM_ATTN, stream>>>(adj, sta, dyn, Whi, cterm, v, logits);
    softmax_kernel<<<BB, 256, 0, stream>>>(logits);
}